// Round 14
// baseline (31.913 us; speedup 1.0000x reference)
//
#include <hip/hip_runtime.h>

#define NRAYS   16384
#define WPB     4
#define GRID    2048     // 2 rays per wave: ray, ray+8192
#define RSTRIDE 8192

typedef _Float16 f16x2 __attribute__((ext_vector_type(2)));
typedef _Float16 f16x4 __attribute__((ext_vector_type(4)));
typedef _Float16 f16x8 __attribute__((ext_vector_type(8)));
typedef float    f32x4 __attribute__((ext_vector_type(4)));

static __device__ __forceinline__ f16x2 pk(float a, float b) {
    return __builtin_bit_cast(f16x2, __builtin_amdgcn_cvt_pkrtz(a, b));
}
static __device__ __forceinline__ f16x4 cat2(f16x2 lo, f16x2 hi) {
    return __builtin_shufflevector(lo, hi, 0, 1, 2, 3);
}
static __device__ __forceinline__ f16x4 pack4relu(f32x4 v) {
    f16x4 p = cat2(pk(v[0], v[1]), pk(v[2], v[3]));
    return __builtin_elementwise_max(p, (f16x4){});
}
template <int CTRL, int RMASK>
static __device__ __forceinline__ float dppadd(float x) {
    int t = __builtin_amdgcn_update_dpp(0, __builtin_bit_cast(int, x), CTRL, RMASK, 0xf, true);
    return x + __builtin_bit_cast(float, t);
}
static __device__ __forceinline__ float wavescan(float x) {
    x = dppadd<0x111, 0xf>(x);   // row_shr:1
    x = dppadd<0x112, 0xf>(x);   // row_shr:2
    x = dppadd<0x114, 0xf>(x);   // row_shr:4
    x = dppadd<0x118, 0xf>(x);   // row_shr:8
    x = dppadd<0x142, 0xa>(x);   // row_bcast:15 -> rows 1,3
    x = dppadd<0x143, 0xc>(x);   // row_bcast:31 -> rows 2,3
    return x;
}
static __device__ __forceinline__ float lane63(float x) {
    return __builtin_bit_cast(float, __builtin_amdgcn_readlane(__builtin_bit_cast(int, x), 63));
}
// XOR-swizzled pointer to 16B chunk `ch` (0..3) of row `row` in a [64][32]-f16 tile
static __device__ __forceinline__ _Float16* rowp(_Float16* b, int row, int ch) {
    return b + (row << 5) + ((ch ^ (row & 3)) << 3);
}

#define MFMA32(a, b, c) __builtin_amdgcn_mfma_f32_16x16x32_f16(a, b, c, 0, 0, 0)
#define MFMA16(a, b, c) __builtin_amdgcn_mfma_f32_16x16x16f16(a, b, c, 0, 0, 0)

// ---------- prep: per-lane weight-fragment blob into d_ws (4 blocks) ----------
extern "C" __global__ void prep_frags(
    const float* __restrict__ W1, const float* __restrict__ b1,
    const float* __restrict__ W2, const float* __restrict__ b2,
    const float* __restrict__ Wr1, const float* __restrict__ br1,
    const float* __restrict__ Wr2, const float* __restrict__ br2,
    void* __restrict__ ws)
{
    _Float16* wsh = (_Float16*)ws;
    float*    wsf = (float*)ws;
    const int b = blockIdx.x;
    const int tid = threadIdx.x;
    const int l = tid & 63, g = tid >> 6;
    const int c = l & 15, q = l >> 4;
    if (b == 0) {
        const int m = g;
        #pragma unroll
        for (int e = 0; e < 8; ++e) {
            const int k = q * 8 + e;
            const float v = (k < 19) ? W1[k * 64 + m * 16 + c]
                                     : (k == 19 ? b1[m * 16 + c] : 0.f);
            wsh[(m * 64 + l) * 8 + e] = (_Float16)v;
        }
    } else if (b == 1) {
        const int mh = g;
        #pragma unroll
        for (int e = 0; e < 4; ++e) {
            wsh[2048 + (mh * 64 + l) * 4 + e] = (_Float16)W2[(mh * 16 + q * 4 + e) * 16 + c];
            wsh[5120 + (mh * 64 + l) * 4 + e] =
                (c < 3) ? (_Float16)Wr2[(mh * 16 + q * 4 + e) * 3 + c] : (_Float16)0.f;
        }
    } else if (b == 2) {
        const int mh = g;
        #pragma unroll
        for (int ks = 0; ks < 2; ++ks)
            #pragma unroll
            for (int e = 0; e < 4; ++e) {
                const int k = ks * 16 + q * 4 + e;
                const float v = (k < 18) ? Wr1[k * 64 + mh * 16 + c]
                                         : (k == 18 ? br1[mh * 16 + c] : 0.f);
                wsh[3072 + ((mh * 2 + ks) * 64 + l) * 4 + e] = (_Float16)v;
            }
    } else {
        if (g == 0) {
            #pragma unroll
            for (int j = 0; j < 4; ++j) wsf[3072 + l * 4 + j] = b2[q * 4 + j];
        } else if (g == 1) {
            #pragma unroll
            for (int j = 0; j < 4; ++j)
                wsf[3328 + l * 4 + j] = ((q * 4 + j) < 3) ? br2[q * 4 + j] : 0.f;
        }
    }
}

// ---------- main ----------
extern "C" __global__ __launch_bounds__(256, 4) void nerf_render_mfma(
    const float* __restrict__ rays_o,
    const float* __restrict__ rays_d,
    const int*   __restrict__ vox_idx,
    const float* __restrict__ t_near,
    const float* __restrict__ t_far,
    const float* __restrict__ embed,
    const void*  __restrict__ ws,
    float* __restrict__ out)
{
    __shared__ __align__(16) _Float16 buf_all[WPB][64 * 32];   // 4KB/wave x-stage tile
    __shared__ __align__(16) f32x4    hof_all[WPB][64];        // 1KB/wave rgb handoff
    __shared__ float                  sdf_all[WPB][64];        // 256B/wave sdf handoff

    const _Float16* frag  = (const _Float16*)ws;
    const float*    fragf = (const float*)ws;

    const int lane = threadIdx.x & 63;
    const int wv   = threadIdx.x >> 6;
    _Float16* buf = buf_all[wv];
    f32x4* hof = hof_all[wv];
    float* sdfb = sdf_all[wv];

    const int c  = lane & 15;
    const int q  = lane >> 4;
    const bool q0 = (q == 0);
    const int hh = lane >> 2, ss = lane & 3;
    const int bpaddr = ((lane + 48) & 63) << 2;                // lane-16 (mod 64), byte addr

    const int ray0 = blockIdx.x * WPB + wv;

    // zero chunk 3 once (k=24..31 of x stays 0 for both rays)
    *(f16x8*)rowp(buf, lane, 3) = (f16x8){};

    float* out_rgb   = out;
    float* out_depth = out + NRAYS * 3;
    float* out_disp  = out_depth + NRAYS;
    float* out_acc   = out_disp + NRAYS;
    float* out_w     = out_acc + NRAYS;
    float* out_sdf   = out_w + NRAYS * 64;

    const f32x4 b2v  = *(const f32x4*)(fragf + 3072 + lane * 4);
    const f32x4 br2v = *(const f32x4*)(fragf + 3328 + lane * 4);

    // ---- fully unrolled 2-ray loop: scheduler hoists ray-2 global loads ----
    #pragma unroll
    for (int it = 0; it < 2; ++it) {
        const int ray = ray0 + it * RSTRIDE;

        // ray loads (longest chain: vox -> embed gather)
        const int   vi_raw = vox_idx[ray * 16 + hh];
        const float tn  = t_near[ray * 16 + hh];
        const float tfv = t_far [ray * 16 + hh];
        const float ox = rays_o[ray*3+0], oy = rays_o[ray*3+1], oz = rays_o[ray*3+2];
        const float dx = rays_d[ray*3+0], dy = rays_d[ray*3+1], dz = rays_d[ray*3+2];
        const int vi0 = vi_raw >= 0 ? vi_raw : 0;
        const float4* er = reinterpret_cast<const float4*>(embed + (long long)vi0 * 16);
        const float4 e0 = er[0], e1 = er[1], e2 = er[2], e3 = er[3];

        // per-sample derived values
        const bool  mask = vi_raw >= 0;
        const float seg  = tfv - tn;
        const float t    = fmaf(seg, ((float)ss + 0.5f) * 0.25f, tn);
        const float dist = seg * 0.25f;
        const float p0 = fmaf(t, dx, ox), p1 = fmaf(t, dy, oy), p2 = fmaf(t, dz, oz);

        // stage x = [p(3), emb(16), 1] (chunks 0..2)
        f16x8 r0 = {(_Float16)p0,   (_Float16)p1,   (_Float16)p2,   (_Float16)e0.x,
                    (_Float16)e0.y, (_Float16)e0.z, (_Float16)e0.w, (_Float16)e1.x};
        f16x8 r1 = {(_Float16)e1.y, (_Float16)e1.z, (_Float16)e1.w, (_Float16)e2.x,
                    (_Float16)e2.y, (_Float16)e2.z, (_Float16)e2.w, (_Float16)e3.x};
        f16x8 r2 = {(_Float16)e3.y, (_Float16)e3.z, (_Float16)e3.w, (_Float16)1.0f,
                    (_Float16)0.0f, (_Float16)0.0f, (_Float16)0.0f, (_Float16)0.0f};
        *(f16x8*)rowp(buf, lane, 0) = r0;
        *(f16x8*)rowp(buf, lane, 1) = r1;
        *(f16x8*)rowp(buf, lane, 2) = r2;

        // B-fragments of x
        f16x8 bx[4];
        #pragma unroll
        for (int n = 0; n < 4; ++n)
            bx[n] = *(const f16x8*)rowp(buf, n * 16 + c, q);

        // L1 (x32) fused with L2 (x16), fully unrolled
        f32x4 acc2[4];
        #pragma unroll
        for (int n = 0; n < 4; ++n) acc2[n] = b2v;
        #pragma unroll
        for (int m = 0; m < 4; ++m) {
            const f16x8 w1f = *(const f16x8*)(frag + (m * 64 + lane) * 8);
            const f16x4 w2a = *(const f16x4*)(frag + 2048 + (m * 64 + lane) * 4);
            #pragma unroll
            for (int np = 0; np < 2; ++np) {
                f32x4 a1[2] = {};
                #pragma unroll
                for (int i = 0; i < 2; ++i) a1[i] = MFMA32(w1f, bx[np * 2 + i], a1[i]);
                #pragma unroll
                for (int i = 0; i < 2; ++i) {
                    const f16x4 hb = pack4relu(a1[i]);
                    acc2[np * 2 + i] = MFMA16(w2a, hb, acc2[np * 2 + i]);
                }
            }
        }

        // build L3 B-fragments: xr^T over [dir(3),feats(15),1]
        float sdfv[4]; f16x2 d0[4], d1[4]; int bd[4];
        #pragma unroll
        for (int n = 0; n < 4; ++n) {
            sdfv[n] = acc2[n][0];
            d0[n] = pk(acc2[n][0], acc2[n][1]);
            d1[n] = pk(acc2[n][2], acc2[n][3]);
        }
        #pragma unroll
        for (int n = 0; n < 4; ++n)
            bd[n] = __builtin_amdgcn_ds_bpermute(bpaddr, __builtin_bit_cast(int, d1[n]));

        // early sdf handoff (wave-private LDS slot)
        if (q0) {
            #pragma unroll
            for (int n = 0; n < 4; ++n) sdfb[n * 16 + c] = sdfv[n];
        }

        const f16x2 dir01 = pk(dx, dy);
        const _Float16 dzh = (_Float16)dz;
        const f16x2 zero2 = {};
        const f16x2 onezero = {(_Float16)1.0f, (_Float16)0.0f};
        f16x4 bfr0[4], bfr1[4];
        #pragma unroll
        for (int n = 0; n < 4; ++n) {
            f16x2 bdn = __builtin_bit_cast(f16x2, bd[n]);
            f16x2 lo0 = q0 ? dir01 : bdn;
            f16x2 hi0 = q0 ? (f16x2){dzh, d0[n][1]} : d0[n];
            bfr0[n] = cat2(lo0, hi0);
            f16x2 lo1 = q0 ? bdn : zero2;
            f16x2 hi1 = q0 ? onezero : zero2;
            bfr1[n] = cat2(lo1, hi1);
        }

        // SDF-side epilogue NOW (independent of L3/L4)
        const float sdfs = sdfb[lane];
        const float mf = mask ? 1.0f : 0.0f;
        const float density = 10.0f / (1.0f + __expf(10.0f * sdfs));
        const float fe      = density * dist * mf;
        const float sdf_sc  = sdfs * mf;

        const float cum   = wavescan(fe);
        const float T     = __expf(fe - cum);
        const float alpha = 1.0f - __expf(-fe);
        const float w     = alpha * T;

        const float swt = lane63(wavescan(w * t));
        const float swa = lane63(wavescan(w));

        const bool hm = (__ballot((int)mask) != 0ull);

        out_w  [ray * 64 + lane] = hm ? w      : 0.0f;
        out_sdf[ray * 64 + lane] = hm ? sdf_sc : 1.0f;
        if (lane == 0) {
            if (hm) {
                out_depth[ray] = swt;
                out_acc[ray]   = swa;
                const float dd = swt / fmaxf(swa, 1e-10f);
                out_disp[ray]  = 1.0f / fmaxf(1e-10f, dd);
            } else {
                out_depth[ray] = 0.0f;
                out_acc[ray]   = 0.0f;
                out_disp[ray]  = 1000.0f;
            }
        }

        // L3 (x16, 2 k-steps) fused with L4 (x16), fully unrolled
        f32x4 acc4[4];
        #pragma unroll
        for (int n = 0; n < 4; ++n) acc4[n] = br2v;
        #pragma unroll
        for (int mh = 0; mh < 4; ++mh) {
            const f16x4 wa0 = *(const f16x4*)(frag + 3072 + ((mh * 2 + 0) * 64 + lane) * 4);
            const f16x4 wa1 = *(const f16x4*)(frag + 3072 + ((mh * 2 + 1) * 64 + lane) * 4);
            const f16x4 w4  = *(const f16x4*)(frag + 5120 + (mh * 64 + lane) * 4);
            #pragma unroll
            for (int np = 0; np < 2; ++np) {
                f32x4 a3[2] = {};
                #pragma unroll
                for (int i = 0; i < 2; ++i) a3[i] = MFMA16(wa0, bfr0[np * 2 + i], a3[i]);
                #pragma unroll
                for (int i = 0; i < 2; ++i) a3[i] = MFMA16(wa1, bfr1[np * 2 + i], a3[i]);
                #pragma unroll
                for (int i = 0; i < 2; ++i) {
                    const f16x4 hr = pack4relu(a3[i]);
                    acc4[np * 2 + i] = MFMA16(w4, hr, acc4[np * 2 + i]);
                }
            }
        }

        // rgb handoff
        if (q0) {
            #pragma unroll
            for (int n = 0; n < 4; ++n) {
                f32x4 o4 = {acc4[n][0], acc4[n][1], acc4[n][2], 0.0f};
                hof[n * 16 + c] = o4;
            }
        }
        const f32x4 mine = hof[lane];

        // rgb tail: sigmoids + 3 scans
        const float rr = mf / (1.0f + __expf(-mine[0]));
        const float gg = mf / (1.0f + __expf(-mine[1]));
        const float bb = mf / (1.0f + __expf(-mine[2]));

        const float swr = lane63(wavescan(w * rr));
        const float swg = lane63(wavescan(w * gg));
        const float swb = lane63(wavescan(w * bb));

        if (lane == 0) {
            if (hm) {
                out_rgb[ray * 3 + 0] = swr;
                out_rgb[ray * 3 + 1] = swg;
                out_rgb[ray * 3 + 2] = swb;
            } else {
                out_rgb[ray * 3 + 0] = 0.0f;
                out_rgb[ray * 3 + 1] = 0.0f;
                out_rgb[ray * 3 + 2] = 0.0f;
            }
        }
    }
}

extern "C" void kernel_launch(void* const* d_in, const int* in_sizes, int n_in,
                              void* d_out, int out_size, void* d_ws, size_t ws_size,
                              hipStream_t stream) {
    const float* rays_o = (const float*)d_in[0];
    const float* rays_d = (const float*)d_in[1];
    const int*   vox    = (const int*)  d_in[2];
    const float* t_near = (const float*)d_in[3];
    const float* t_far  = (const float*)d_in[4];
    // d_in[5] = ray_hits (bool) — recomputed on device
    const float* embed  = (const float*)d_in[6];
    const float* W1  = (const float*)d_in[7];
    const float* b1  = (const float*)d_in[8];
    const float* W2  = (const float*)d_in[9];
    const float* b2  = (const float*)d_in[10];
    const float* Wr1 = (const float*)d_in[11];
    const float* br1 = (const float*)d_in[12];
    const float* Wr2 = (const float*)d_in[13];
    const float* br2 = (const float*)d_in[14];
    float* outp = (float*)d_out;

    prep_frags<<<dim3(4), dim3(256), 0, stream>>>(W1, b1, W2, b2, Wr1, br1, Wr2, br2, d_ws);
    nerf_render_mfma<<<dim3(GRID), dim3(256), 0, stream>>>(rays_o, rays_d, vox, t_near, t_far,
                                                           embed, d_ws, outp);
}

// Round 15
// 30.511 us; speedup vs baseline: 1.0460x; 1.0460x over previous
//
#include <hip/hip_runtime.h>

#define NRAYS  16384
#define WPB    4
#define GRID   4096      // 1 ray per wave

typedef _Float16 f16x2 __attribute__((ext_vector_type(2)));
typedef _Float16 f16x4 __attribute__((ext_vector_type(4)));
typedef _Float16 f16x8 __attribute__((ext_vector_type(8)));
typedef float    f32x4 __attribute__((ext_vector_type(4)));

static __device__ __forceinline__ f16x2 pk(float a, float b) {
    return __builtin_bit_cast(f16x2, __builtin_amdgcn_cvt_pkrtz(a, b));
}
static __device__ __forceinline__ f16x4 cat2(f16x2 lo, f16x2 hi) {
    return __builtin_shufflevector(lo, hi, 0, 1, 2, 3);
}
static __device__ __forceinline__ f16x4 pack4relu(f32x4 v) {
    f16x4 p = cat2(pk(v[0], v[1]), pk(v[2], v[3]));
    return __builtin_elementwise_max(p, (f16x4){});
}
template <int CTRL, int RMASK>
static __device__ __forceinline__ float dppadd(float x) {
    int t = __builtin_amdgcn_update_dpp(0, __builtin_bit_cast(int, x), CTRL, RMASK, 0xf, true);
    return x + __builtin_bit_cast(float, t);
}
static __device__ __forceinline__ float wavescan(float x) {
    x = dppadd<0x111, 0xf>(x);   // row_shr:1
    x = dppadd<0x112, 0xf>(x);   // row_shr:2
    x = dppadd<0x114, 0xf>(x);   // row_shr:4
    x = dppadd<0x118, 0xf>(x);   // row_shr:8
    x = dppadd<0x142, 0xa>(x);   // row_bcast:15 -> rows 1,3
    x = dppadd<0x143, 0xc>(x);   // row_bcast:31 -> rows 2,3
    return x;
}
static __device__ __forceinline__ float lane63(float x) {
    return __builtin_bit_cast(float, __builtin_amdgcn_readlane(__builtin_bit_cast(int, x), 63));
}
// XOR-swizzled pointer to 16B chunk `ch` (0..3) of row `row` in a [64][32]-f16 tile
static __device__ __forceinline__ _Float16* rowp(_Float16* b, int row, int ch) {
    return b + (row << 5) + ((ch ^ (row & 3)) << 3);
}

#define MFMA32(a, b, c) __builtin_amdgcn_mfma_f32_16x16x32_f16(a, b, c, 0, 0, 0)
#define MFMA16(a, b, c) __builtin_amdgcn_mfma_f32_16x16x16f16(a, b, c, 0, 0, 0)

// ---------- prep: per-lane weight-fragment blob into d_ws (4 blocks) ----------
extern "C" __global__ void prep_frags(
    const float* __restrict__ W1, const float* __restrict__ b1,
    const float* __restrict__ W2, const float* __restrict__ b2,
    const float* __restrict__ Wr1, const float* __restrict__ br1,
    const float* __restrict__ Wr2, const float* __restrict__ br2,
    void* __restrict__ ws)
{
    _Float16* wsh = (_Float16*)ws;
    float*    wsf = (float*)ws;
    const int b = blockIdx.x;
    const int tid = threadIdx.x;
    const int l = tid & 63, g = tid >> 6;
    const int c = l & 15, q = l >> 4;
    if (b == 0) {
        const int m = g;
        #pragma unroll
        for (int e = 0; e < 8; ++e) {
            const int k = q * 8 + e;
            const float v = (k < 19) ? W1[k * 64 + m * 16 + c]
                                     : (k == 19 ? b1[m * 16 + c] : 0.f);
            wsh[(m * 64 + l) * 8 + e] = (_Float16)v;
        }
    } else if (b == 1) {
        const int mh = g;
        #pragma unroll
        for (int e = 0; e < 4; ++e) {
            wsh[2048 + (mh * 64 + l) * 4 + e] = (_Float16)W2[(mh * 16 + q * 4 + e) * 16 + c];
            wsh[5120 + (mh * 64 + l) * 4 + e] =
                (c < 3) ? (_Float16)Wr2[(mh * 16 + q * 4 + e) * 3 + c] : (_Float16)0.f;
        }
    } else if (b == 2) {
        const int mh = g;
        #pragma unroll
        for (int ks = 0; ks < 2; ++ks)
            #pragma unroll
            for (int e = 0; e < 4; ++e) {
                const int k = ks * 16 + q * 4 + e;
                const float v = (k < 18) ? Wr1[k * 64 + mh * 16 + c]
                                         : (k == 18 ? br1[mh * 16 + c] : 0.f);
                wsh[3072 + ((mh * 2 + ks) * 64 + l) * 4 + e] = (_Float16)v;
            }
    } else {
        if (g == 0) {
            #pragma unroll
            for (int j = 0; j < 4; ++j) wsf[3072 + l * 4 + j] = b2[q * 4 + j];
        } else if (g == 1) {
            #pragma unroll
            for (int j = 0; j < 4; ++j)
                wsf[3328 + l * 4 + j] = ((q * 4 + j) < 3) ? br2[q * 4 + j] : 0.f;
        }
    }
}

// ---------- main ----------
extern "C" __global__ __launch_bounds__(256, 4) void nerf_render_mfma(
    const float* __restrict__ rays_o,
    const float* __restrict__ rays_d,
    const int*   __restrict__ vox_idx,
    const float* __restrict__ t_near,
    const float* __restrict__ t_far,
    const float* __restrict__ embed,
    const void*  __restrict__ ws,
    float* __restrict__ out)
{
    __shared__ __align__(16) _Float16 buf_all[WPB][64 * 32];   // 4KB/wave x-stage tile
    __shared__ __align__(16) f32x4    hof_all[WPB][64];        // 1KB/wave rgb handoff
    __shared__ float                  sdf_all[WPB][64];        // 256B/wave sdf handoff

    const _Float16* frag  = (const _Float16*)ws;
    const float*    fragf = (const float*)ws;

    const int lane = threadIdx.x & 63;
    const int wv   = threadIdx.x >> 6;
    _Float16* buf = buf_all[wv];
    f32x4* hof = hof_all[wv];
    float* sdfb = sdf_all[wv];

    const int c  = lane & 15;
    const int q  = lane >> 4;
    const bool q0 = (q == 0);
    const int hh = lane >> 2, ss = lane & 3;
    const int bpaddr = ((lane + 48) & 63) << 2;                // lane-16 (mod 64), byte addr

    const int ray = blockIdx.x * WPB + wv;

    // ---- ray loads first (longest chain: vox -> embed gather) ----
    const int   vi_raw = vox_idx[ray * 16 + hh];
    const float tn  = t_near[ray * 16 + hh];
    const float tfv = t_far [ray * 16 + hh];
    const float ox = rays_o[ray*3+0], oy = rays_o[ray*3+1], oz = rays_o[ray*3+2];
    const float dx = rays_d[ray*3+0], dy = rays_d[ray*3+1], dz = rays_d[ray*3+2];
    const int vi0 = vi_raw >= 0 ? vi_raw : 0;
    const float4* er = reinterpret_cast<const float4*>(embed + (long long)vi0 * 16);
    const float4 e0 = er[0], e1 = er[1], e2 = er[2], e3 = er[3];

    // zero chunk 3 (k=24..31 of x stays 0)
    *(f16x8*)rowp(buf, lane, 3) = (f16x8){};

    // ---- per-sample derived values ----
    const bool  mask = vi_raw >= 0;
    const float seg  = tfv - tn;
    const float t    = fmaf(seg, ((float)ss + 0.5f) * 0.25f, tn);
    const float dist = seg * 0.25f;
    const float p0 = fmaf(t, dx, ox), p1 = fmaf(t, dy, oy), p2 = fmaf(t, dz, oz);

    // ---- stage x = [p(3), emb(16), 1] (chunks 0..2) ----
    f16x8 r0 = {(_Float16)p0,   (_Float16)p1,   (_Float16)p2,   (_Float16)e0.x,
                (_Float16)e0.y, (_Float16)e0.z, (_Float16)e0.w, (_Float16)e1.x};
    f16x8 r1 = {(_Float16)e1.y, (_Float16)e1.z, (_Float16)e1.w, (_Float16)e2.x,
                (_Float16)e2.y, (_Float16)e2.z, (_Float16)e2.w, (_Float16)e3.x};
    f16x8 r2 = {(_Float16)e3.y, (_Float16)e3.z, (_Float16)e3.w, (_Float16)1.0f,
                (_Float16)0.0f, (_Float16)0.0f, (_Float16)0.0f, (_Float16)0.0f};
    *(f16x8*)rowp(buf, lane, 0) = r0;
    *(f16x8*)rowp(buf, lane, 1) = r1;
    *(f16x8*)rowp(buf, lane, 2) = r2;

    // ---- B-fragments of x ----
    f16x8 bx[4];
    #pragma unroll
    for (int n = 0; n < 4; ++n)
        bx[n] = *(const f16x8*)rowp(buf, n * 16 + c, q);

    // ---- L1 (x32) fused with L2 (x16), fully unrolled; setprio around MFMAs ----
    const f32x4 b2v = *(const f32x4*)(fragf + 3072 + lane * 4);
    f32x4 acc2[4];
    #pragma unroll
    for (int n = 0; n < 4; ++n) acc2[n] = b2v;
    __builtin_amdgcn_s_setprio(1);
    #pragma unroll
    for (int m = 0; m < 4; ++m) {
        const f16x8 w1f = *(const f16x8*)(frag + (m * 64 + lane) * 8);
        const f16x4 w2a = *(const f16x4*)(frag + 2048 + (m * 64 + lane) * 4);
        #pragma unroll
        for (int np = 0; np < 2; ++np) {
            f32x4 a1[2] = {};
            #pragma unroll
            for (int i = 0; i < 2; ++i) a1[i] = MFMA32(w1f, bx[np * 2 + i], a1[i]);
            #pragma unroll
            for (int i = 0; i < 2; ++i) {
                const f16x4 hb = pack4relu(a1[i]);
                acc2[np * 2 + i] = MFMA16(w2a, hb, acc2[np * 2 + i]);
            }
        }
    }
    __builtin_amdgcn_s_setprio(0);

    // ---- build L3 B-fragments: xr^T over [dir(3),feats(15),1] ----
    float sdfv[4]; f16x2 d0[4], d1[4]; int bd[4];
    #pragma unroll
    for (int n = 0; n < 4; ++n) {
        sdfv[n] = acc2[n][0];
        d0[n] = pk(acc2[n][0], acc2[n][1]);
        d1[n] = pk(acc2[n][2], acc2[n][3]);
    }
    #pragma unroll
    for (int n = 0; n < 4; ++n)
        bd[n] = __builtin_amdgcn_ds_bpermute(bpaddr, __builtin_bit_cast(int, d1[n]));

    // ---- early sdf handoff (separate LDS slot; wave-private) ----
    if (q0) {
        #pragma unroll
        for (int n = 0; n < 4; ++n) sdfb[n * 16 + c] = sdfv[n];
    }

    const f16x2 dir01 = pk(dx, dy);
    const _Float16 dzh = (_Float16)dz;
    const f16x2 zero2 = {};
    const f16x2 onezero = {(_Float16)1.0f, (_Float16)0.0f};
    f16x4 bfr0[4], bfr1[4];
    #pragma unroll
    for (int n = 0; n < 4; ++n) {
        f16x2 bdn = __builtin_bit_cast(f16x2, bd[n]);
        f16x2 lo0 = q0 ? dir01 : bdn;
        f16x2 hi0 = q0 ? (f16x2){dzh, d0[n][1]} : d0[n];
        bfr0[n] = cat2(lo0, hi0);
        f16x2 lo1 = q0 ? bdn : zero2;
        f16x2 hi1 = q0 ? onezero : zero2;
        bfr1[n] = cat2(lo1, hi1);
    }

    float* out_rgb   = out;
    float* out_depth = out + NRAYS * 3;
    float* out_disp  = out_depth + NRAYS;
    float* out_acc   = out_disp + NRAYS;
    float* out_w     = out_acc + NRAYS;
    float* out_sdf   = out_w + NRAYS * 64;

    // ---- SDF-side epilogue NOW (independent of L3/L4; overlaps cross-wave) ----
    const float sdfs = sdfb[lane];
    const float mf = mask ? 1.0f : 0.0f;
    const float density = 10.0f / (1.0f + __expf(10.0f * sdfs));
    const float fe      = density * dist * mf;
    const float sdf_sc  = sdfs * mf;

    const float cum   = wavescan(fe);
    const float T     = __expf(fe - cum);
    const float alpha = 1.0f - __expf(-fe);
    const float w     = alpha * T;

    const float swt = lane63(wavescan(w * t));
    const float swa = lane63(wavescan(w));

    const bool hm = (__ballot((int)mask) != 0ull);

    out_w  [ray * 64 + lane] = hm ? w      : 0.0f;
    out_sdf[ray * 64 + lane] = hm ? sdf_sc : 1.0f;
    if (lane == 0) {
        if (hm) {
            out_depth[ray] = swt;
            out_acc[ray]   = swa;
            const float dd = swt / fmaxf(swa, 1e-10f);
            out_disp[ray]  = 1.0f / fmaxf(1e-10f, dd);
        } else {
            out_depth[ray] = 0.0f;
            out_acc[ray]   = 0.0f;
            out_disp[ray]  = 1000.0f;
        }
    }

    // ---- L3 (x16, 2 k-steps) fused with L4 (x16), fully unrolled; setprio ----
    const f32x4 br2v = *(const f32x4*)(fragf + 3328 + lane * 4);
    f32x4 acc4[4];
    #pragma unroll
    for (int n = 0; n < 4; ++n) acc4[n] = br2v;
    __builtin_amdgcn_s_setprio(1);
    #pragma unroll
    for (int mh = 0; mh < 4; ++mh) {
        const f16x4 wa0 = *(const f16x4*)(frag + 3072 + ((mh * 2 + 0) * 64 + lane) * 4);
        const f16x4 wa1 = *(const f16x4*)(frag + 3072 + ((mh * 2 + 1) * 64 + lane) * 4);
        const f16x4 w4  = *(const f16x4*)(frag + 5120 + (mh * 64 + lane) * 4);
        #pragma unroll
        for (int np = 0; np < 2; ++np) {
            f32x4 a3[2] = {};
            #pragma unroll
            for (int i = 0; i < 2; ++i) a3[i] = MFMA16(wa0, bfr0[np * 2 + i], a3[i]);
            #pragma unroll
            for (int i = 0; i < 2; ++i) a3[i] = MFMA16(wa1, bfr1[np * 2 + i], a3[i]);
            #pragma unroll
            for (int i = 0; i < 2; ++i) {
                const f16x4 hr = pack4relu(a3[i]);
                acc4[np * 2 + i] = MFMA16(w4, hr, acc4[np * 2 + i]);
            }
        }
    }
    __builtin_amdgcn_s_setprio(0);

    // ---- rgb handoff ----
    if (q0) {
        #pragma unroll
        for (int n = 0; n < 4; ++n) {
            f32x4 o4 = {acc4[n][0], acc4[n][1], acc4[n][2], 0.0f};
            hof[n * 16 + c] = o4;
        }
    }
    const f32x4 mine = hof[lane];

    // ---- rgb tail: sigmoids + 3 scans ----
    const float rr = mf / (1.0f + __expf(-mine[0]));
    const float gg = mf / (1.0f + __expf(-mine[1]));
    const float bb = mf / (1.0f + __expf(-mine[2]));

    const float swr = lane63(wavescan(w * rr));
    const float swg = lane63(wavescan(w * gg));
    const float swb = lane63(wavescan(w * bb));

    if (lane == 0) {
        if (hm) {
            out_rgb[ray * 3 + 0] = swr;
            out_rgb[ray * 3 + 1] = swg;
            out_rgb[ray * 3 + 2] = swb;
        } else {
            out_rgb[ray * 3 + 0] = 0.0f;
            out_rgb[ray * 3 + 1] = 0.0f;
            out_rgb[ray * 3 + 2] = 0.0f;
        }
    }
}

extern "C" void kernel_launch(void* const* d_in, const int* in_sizes, int n_in,
                              void* d_out, int out_size, void* d_ws, size_t ws_size,
                              hipStream_t stream) {
    const float* rays_o = (const float*)d_in[0];
    const float* rays_d = (const float*)d_in[1];
    const int*   vox    = (const int*)  d_in[2];
    const float* t_near = (const float*)d_in[3];
    const float* t_far  = (const float*)d_in[4];
    // d_in[5] = ray_hits (bool) — recomputed on device
    const float* embed  = (const float*)d_in[6];
    const float* W1  = (const float*)d_in[7];
    const float* b1  = (const float*)d_in[8];
    const float* W2  = (const float*)d_in[9];
    const float* b2  = (const float*)d_in[10];
    const float* Wr1 = (const float*)d_in[11];
    const float* br1 = (const float*)d_in[12];
    const float* Wr2 = (const float*)d_in[13];
    const float* br2 = (const float*)d_in[14];
    float* outp = (float*)d_out;

    prep_frags<<<dim3(4), dim3(256), 0, stream>>>(W1, b1, W2, b2, Wr1, br1, Wr2, br2, d_ws);
    nerf_render_mfma<<<dim3(GRID), dim3(256), 0, stream>>>(rays_o, rays_d, vox, t_near, t_far,
                                                           embed, d_ws, outp);
}

// Round 16
// 29.822 us; speedup vs baseline: 1.0701x; 1.0231x over previous
//
#include <hip/hip_runtime.h>

#define NRAYS  16384
#define WPB    4
#define GRID   4096      // 1 ray per wave

typedef _Float16 f16x2 __attribute__((ext_vector_type(2)));
typedef _Float16 f16x4 __attribute__((ext_vector_type(4)));
typedef _Float16 f16x8 __attribute__((ext_vector_type(8)));
typedef float    f32x4 __attribute__((ext_vector_type(4)));

static __device__ __forceinline__ f16x2 pk(float a, float b) {
    return __builtin_bit_cast(f16x2, __builtin_amdgcn_cvt_pkrtz(a, b));
}
static __device__ __forceinline__ f16x4 cat2(f16x2 lo, f16x2 hi) {
    return __builtin_shufflevector(lo, hi, 0, 1, 2, 3);
}
static __device__ __forceinline__ f16x4 pack4relu(f32x4 v) {
    f16x4 p = cat2(pk(v[0], v[1]), pk(v[2], v[3]));
    return __builtin_elementwise_max(p, (f16x4){});
}
template <int CTRL, int RMASK>
static __device__ __forceinline__ float dppadd(float x) {
    int t = __builtin_amdgcn_update_dpp(0, __builtin_bit_cast(int, x), CTRL, RMASK, 0xf, true);
    return x + __builtin_bit_cast(float, t);
}
static __device__ __forceinline__ float wavescan(float x) {
    x = dppadd<0x111, 0xf>(x);   // row_shr:1
    x = dppadd<0x112, 0xf>(x);   // row_shr:2
    x = dppadd<0x114, 0xf>(x);   // row_shr:4
    x = dppadd<0x118, 0xf>(x);   // row_shr:8
    x = dppadd<0x142, 0xa>(x);   // row_bcast:15 -> rows 1,3
    x = dppadd<0x143, 0xc>(x);   // row_bcast:31 -> rows 2,3
    return x;
}
static __device__ __forceinline__ float lane63(float x) {
    return __builtin_bit_cast(float, __builtin_amdgcn_readlane(__builtin_bit_cast(int, x), 63));
}
// XOR-swizzled pointer to 16B chunk `ch` (0..3) of row `row` in a [64][32]-f16 tile
static __device__ __forceinline__ _Float16* rowp(_Float16* b, int row, int ch) {
    return b + (row << 5) + ((ch ^ (row & 3)) << 3);
}

#define MFMA32(a, b, c) __builtin_amdgcn_mfma_f32_16x16x32_f16(a, b, c, 0, 0, 0)
#define MFMA16(a, b, c) __builtin_amdgcn_mfma_f32_16x16x16f16(a, b, c, 0, 0, 0)

// ---------- prep: per-lane weight-fragment blob into d_ws (4 blocks) ----------
extern "C" __global__ void prep_frags(
    const float* __restrict__ W1, const float* __restrict__ b1,
    const float* __restrict__ W2, const float* __restrict__ b2,
    const float* __restrict__ Wr1, const float* __restrict__ br1,
    const float* __restrict__ Wr2, const float* __restrict__ br2,
    void* __restrict__ ws)
{
    _Float16* wsh = (_Float16*)ws;
    float*    wsf = (float*)ws;
    const int b = blockIdx.x;
    const int tid = threadIdx.x;
    const int l = tid & 63, g = tid >> 6;
    const int c = l & 15, q = l >> 4;
    if (b == 0) {
        const int m = g;
        #pragma unroll
        for (int e = 0; e < 8; ++e) {
            const int k = q * 8 + e;
            const float v = (k < 19) ? W1[k * 64 + m * 16 + c]
                                     : (k == 19 ? b1[m * 16 + c] : 0.f);
            wsh[(m * 64 + l) * 8 + e] = (_Float16)v;
        }
    } else if (b == 1) {
        const int mh = g;
        #pragma unroll
        for (int e = 0; e < 4; ++e) {
            wsh[2048 + (mh * 64 + l) * 4 + e] = (_Float16)W2[(mh * 16 + q * 4 + e) * 16 + c];
            wsh[5120 + (mh * 64 + l) * 4 + e] =
                (c < 3) ? (_Float16)Wr2[(mh * 16 + q * 4 + e) * 3 + c] : (_Float16)0.f;
        }
    } else if (b == 2) {
        const int mh = g;
        #pragma unroll
        for (int ks = 0; ks < 2; ++ks)
            #pragma unroll
            for (int e = 0; e < 4; ++e) {
                const int k = ks * 16 + q * 4 + e;
                const float v = (k < 18) ? Wr1[k * 64 + mh * 16 + c]
                                         : (k == 18 ? br1[mh * 16 + c] : 0.f);
                wsh[3072 + ((mh * 2 + ks) * 64 + l) * 4 + e] = (_Float16)v;
            }
    } else {
        if (g == 0) {
            #pragma unroll
            for (int j = 0; j < 4; ++j) wsf[3072 + l * 4 + j] = b2[q * 4 + j];
        } else if (g == 1) {
            #pragma unroll
            for (int j = 0; j < 4; ++j)
                wsf[3328 + l * 4 + j] = ((q * 4 + j) < 3) ? br2[q * 4 + j] : 0.f;
        }
    }
}

// ---------- main ----------
extern "C" __global__ __launch_bounds__(256, 4) void nerf_render_mfma(
    const float* __restrict__ rays_o,
    const float* __restrict__ rays_d,
    const int*   __restrict__ vox_idx,
    const float* __restrict__ t_near,
    const float* __restrict__ t_far,
    const float* __restrict__ embed,
    const void*  __restrict__ ws,
    float* __restrict__ out)
{
    __shared__ __align__(16) _Float16 buf_all[WPB][64 * 32];   // 4KB/wave x-stage tile
    __shared__ __align__(16) f32x4    hof_all[WPB][64];        // 1KB/wave rgb handoff
    __shared__ float                  sdf_all[WPB][64];        // 256B/wave sdf handoff

    const _Float16* frag  = (const _Float16*)ws;
    const float*    fragf = (const float*)ws;

    const int lane = threadIdx.x & 63;
    const int wv   = threadIdx.x >> 6;
    _Float16* buf = buf_all[wv];
    f32x4* hof = hof_all[wv];
    float* sdfb = sdf_all[wv];

    const int c  = lane & 15;
    const int q  = lane >> 4;
    const bool q0 = (q == 0);
    const int hh = lane >> 2, ss = lane & 3;
    const int bpaddr = ((lane + 48) & 63) << 2;                // lane-16 (mod 64), byte addr

    const int ray = blockIdx.x * WPB + wv;

    // ---- ray loads first (longest chain: vox -> embed gather) ----
    const int   vi_raw = vox_idx[ray * 16 + hh];
    const float tn  = t_near[ray * 16 + hh];
    const float tfv = t_far [ray * 16 + hh];
    const float ox = rays_o[ray*3+0], oy = rays_o[ray*3+1], oz = rays_o[ray*3+2];
    const float dx = rays_d[ray*3+0], dy = rays_d[ray*3+1], dz = rays_d[ray*3+2];
    const int vi0 = vi_raw >= 0 ? vi_raw : 0;
    const float4* er = reinterpret_cast<const float4*>(embed + (long long)vi0 * 16);
    const float4 e0 = er[0], e1 = er[1], e2 = er[2], e3 = er[3];

    // zero chunk 3 (k=24..31 of x stays 0)
    *(f16x8*)rowp(buf, lane, 3) = (f16x8){};

    // ---- per-sample derived values ----
    const bool  mask = vi_raw >= 0;
    const float seg  = tfv - tn;
    const float t    = fmaf(seg, ((float)ss + 0.5f) * 0.25f, tn);
    const float dist = seg * 0.25f;
    const float p0 = fmaf(t, dx, ox), p1 = fmaf(t, dy, oy), p2 = fmaf(t, dz, oz);

    // ---- stage x = [p(3), emb(16), 1] (chunks 0..2) ----
    f16x8 r0 = {(_Float16)p0,   (_Float16)p1,   (_Float16)p2,   (_Float16)e0.x,
                (_Float16)e0.y, (_Float16)e0.z, (_Float16)e0.w, (_Float16)e1.x};
    f16x8 r1 = {(_Float16)e1.y, (_Float16)e1.z, (_Float16)e1.w, (_Float16)e2.x,
                (_Float16)e2.y, (_Float16)e2.z, (_Float16)e2.w, (_Float16)e3.x};
    f16x8 r2 = {(_Float16)e3.y, (_Float16)e3.z, (_Float16)e3.w, (_Float16)1.0f,
                (_Float16)0.0f, (_Float16)0.0f, (_Float16)0.0f, (_Float16)0.0f};
    *(f16x8*)rowp(buf, lane, 0) = r0;
    *(f16x8*)rowp(buf, lane, 1) = r1;
    *(f16x8*)rowp(buf, lane, 2) = r2;

    // ---- B-fragments of x ----
    f16x8 bx[4];
    #pragma unroll
    for (int n = 0; n < 4; ++n)
        bx[n] = *(const f16x8*)rowp(buf, n * 16 + c, q);

    // ---- L1 (x32) fused with L2 (x16), fully unrolled (loads batch at top) ----
    const f32x4 b2v = *(const f32x4*)(fragf + 3072 + lane * 4);
    f32x4 acc2[4];
    #pragma unroll
    for (int n = 0; n < 4; ++n) acc2[n] = b2v;
    #pragma unroll
    for (int m = 0; m < 4; ++m) {
        const f16x8 w1f = *(const f16x8*)(frag + (m * 64 + lane) * 8);
        const f16x4 w2a = *(const f16x4*)(frag + 2048 + (m * 64 + lane) * 4);
        #pragma unroll
        for (int np = 0; np < 2; ++np) {
            f32x4 a1[2] = {};
            #pragma unroll
            for (int i = 0; i < 2; ++i) a1[i] = MFMA32(w1f, bx[np * 2 + i], a1[i]);
            #pragma unroll
            for (int i = 0; i < 2; ++i) {
                const f16x4 hb = pack4relu(a1[i]);
                acc2[np * 2 + i] = MFMA16(w2a, hb, acc2[np * 2 + i]);
            }
        }
    }

    // ---- build L3 B-fragments: xr^T over [dir(3),feats(15),1] ----
    float sdfv[4]; f16x2 d0[4], d1[4]; int bd[4];
    #pragma unroll
    for (int n = 0; n < 4; ++n) {
        sdfv[n] = acc2[n][0];
        d0[n] = pk(acc2[n][0], acc2[n][1]);
        d1[n] = pk(acc2[n][2], acc2[n][3]);
    }
    #pragma unroll
    for (int n = 0; n < 4; ++n)
        bd[n] = __builtin_amdgcn_ds_bpermute(bpaddr, __builtin_bit_cast(int, d1[n]));

    // ---- early sdf handoff (separate LDS slot; wave-private) ----
    if (q0) {
        #pragma unroll
        for (int n = 0; n < 4; ++n) sdfb[n * 16 + c] = sdfv[n];
    }

    const f16x2 dir01 = pk(dx, dy);
    const _Float16 dzh = (_Float16)dz;
    const f16x2 zero2 = {};
    const f16x2 onezero = {(_Float16)1.0f, (_Float16)0.0f};
    f16x4 bfr0[4], bfr1[4];
    #pragma unroll
    for (int n = 0; n < 4; ++n) {
        f16x2 bdn = __builtin_bit_cast(f16x2, bd[n]);
        f16x2 lo0 = q0 ? dir01 : bdn;
        f16x2 hi0 = q0 ? (f16x2){dzh, d0[n][1]} : d0[n];
        bfr0[n] = cat2(lo0, hi0);
        f16x2 lo1 = q0 ? bdn : zero2;
        f16x2 hi1 = q0 ? onezero : zero2;
        bfr1[n] = cat2(lo1, hi1);
    }

    float* out_rgb   = out;
    float* out_depth = out + NRAYS * 3;
    float* out_disp  = out_depth + NRAYS;
    float* out_acc   = out_disp + NRAYS;
    float* out_w     = out_acc + NRAYS;
    float* out_sdf   = out_w + NRAYS * 64;

    // ---- SDF-side epilogue NOW (independent of L3/L4; overlaps cross-wave) ----
    const float sdfs = sdfb[lane];
    const float mf = mask ? 1.0f : 0.0f;
    const float density = 10.0f / (1.0f + __expf(10.0f * sdfs));
    const float fe      = density * dist * mf;
    const float sdf_sc  = sdfs * mf;

    const float cum   = wavescan(fe);
    const float T     = __expf(fe - cum);
    const float alpha = 1.0f - __expf(-fe);
    const float w     = alpha * T;

    const float swt = lane63(wavescan(w * t));
    const float swa = lane63(wavescan(w));

    const bool hm = (__ballot((int)mask) != 0ull);

    out_w  [ray * 64 + lane] = hm ? w      : 0.0f;
    out_sdf[ray * 64 + lane] = hm ? sdf_sc : 1.0f;
    if (lane == 0) {
        if (hm) {
            out_depth[ray] = swt;
            out_acc[ray]   = swa;
            const float dd = swt / fmaxf(swa, 1e-10f);
            out_disp[ray]  = 1.0f / fmaxf(1e-10f, dd);
        } else {
            out_depth[ray] = 0.0f;
            out_acc[ray]   = 0.0f;
            out_disp[ray]  = 1000.0f;
        }
    }

    // ---- L3 (x16, 2 k-steps) fused with L4 (x16), fully unrolled ----
    const f32x4 br2v = *(const f32x4*)(fragf + 3328 + lane * 4);
    f32x4 acc4[4];
    #pragma unroll
    for (int n = 0; n < 4; ++n) acc4[n] = br2v;
    #pragma unroll
    for (int mh = 0; mh < 4; ++mh) {
        const f16x4 wa0 = *(const f16x4*)(frag + 3072 + ((mh * 2 + 0) * 64 + lane) * 4);
        const f16x4 wa1 = *(const f16x4*)(frag + 3072 + ((mh * 2 + 1) * 64 + lane) * 4);
        const f16x4 w4  = *(const f16x4*)(frag + 5120 + (mh * 64 + lane) * 4);
        #pragma unroll
        for (int np = 0; np < 2; ++np) {
            f32x4 a3[2] = {};
            #pragma unroll
            for (int i = 0; i < 2; ++i) a3[i] = MFMA16(wa0, bfr0[np * 2 + i], a3[i]);
            #pragma unroll
            for (int i = 0; i < 2; ++i) a3[i] = MFMA16(wa1, bfr1[np * 2 + i], a3[i]);
            #pragma unroll
            for (int i = 0; i < 2; ++i) {
                const f16x4 hr = pack4relu(a3[i]);
                acc4[np * 2 + i] = MFMA16(w4, hr, acc4[np * 2 + i]);
            }
        }
    }

    // ---- rgb handoff ----
    if (q0) {
        #pragma unroll
        for (int n = 0; n < 4; ++n) {
            f32x4 o4 = {acc4[n][0], acc4[n][1], acc4[n][2], 0.0f};
            hof[n * 16 + c] = o4;
        }
    }
    const f32x4 mine = hof[lane];

    // ---- rgb tail: sigmoids + 3 scans ----
    const float rr = mf / (1.0f + __expf(-mine[0]));
    const float gg = mf / (1.0f + __expf(-mine[1]));
    const float bb = mf / (1.0f + __expf(-mine[2]));

    const float swr = lane63(wavescan(w * rr));
    const float swg = lane63(wavescan(w * gg));
    const float swb = lane63(wavescan(w * bb));

    if (lane == 0) {
        if (hm) {
            out_rgb[ray * 3 + 0] = swr;
            out_rgb[ray * 3 + 1] = swg;
            out_rgb[ray * 3 + 2] = swb;
        } else {
            out_rgb[ray * 3 + 0] = 0.0f;
            out_rgb[ray * 3 + 1] = 0.0f;
            out_rgb[ray * 3 + 2] = 0.0f;
        }
    }
}

extern "C" void kernel_launch(void* const* d_in, const int* in_sizes, int n_in,
                              void* d_out, int out_size, void* d_ws, size_t ws_size,
                              hipStream_t stream) {
    const float* rays_o = (const float*)d_in[0];
    const float* rays_d = (const float*)d_in[1];
    const int*   vox    = (const int*)  d_in[2];
    const float* t_near = (const float*)d_in[3];
    const float* t_far  = (const float*)d_in[4];
    // d_in[5] = ray_hits (bool) — recomputed on device
    const float* embed  = (const float*)d_in[6];
    const float* W1  = (const float*)d_in[7];
    const float* b1  = (const float*)d_in[8];
    const float* W2  = (const float*)d_in[9];
    const float* b2  = (const float*)d_in[10];
    const float* Wr1 = (const float*)d_in[11];
    const float* br1 = (const float*)d_in[12];
    const float* Wr2 = (const float*)d_in[13];
    const float* br2 = (const float*)d_in[14];
    float* outp = (float*)d_out;

    prep_frags<<<dim3(4), dim3(256), 0, stream>>>(W1, b1, W2, b2, Wr1, br1, Wr2, br2, d_ws);
    nerf_render_mfma<<<dim3(GRID), dim3(256), 0, stream>>>(rays_o, rays_d, vox, t_near, t_far,
                                                           embed, d_ws, outp);
}